// Round 1
// baseline (1232.135 us; speedup 1.0000x reference)
//
#include <hip/hip_runtime.h>

typedef unsigned short u16;
typedef short bf16x8 __attribute__((ext_vector_type(8)));
typedef float f32x4 __attribute__((ext_vector_type(4)));
typedef u16 u16x8 __attribute__((ext_vector_type(8)));
typedef u16 u16x4 __attribute__((ext_vector_type(4)));

#define B_ 4
#define S_ 4096
#define E_ 1024
#define H_ 16
#define D_ 64
#define M_ 16384
#define N_ 3072
#define K_ 1024

__device__ __forceinline__ u16 f2b(float f) {
    unsigned x = __builtin_bit_cast(unsigned, f);
    return (u16)((x + 0x7fffu + ((x >> 16) & 1u)) >> 16);   // RNE
}
__device__ __forceinline__ float b2f(u16 u) {
    unsigned x = ((unsigned)u) << 16;
    return __builtin_bit_cast(float, x);
}
__device__ __forceinline__ float phi_f(float x) { return x > 0.f ? x + 1.f : __expf(x); }

__device__ __forceinline__ void gload16(const void* g, void* l) {
    __builtin_amdgcn_global_load_lds((const __attribute__((address_space(1))) void*)g,
                                     (__attribute__((address_space(3))) void*)l, 16, 0, 0);
}

// ---------------- kernel 1: fp32 -> bf16 convert ----------------
__global__ void cvt_bf16(const float* __restrict__ in, u16* __restrict__ out, int n8) {
    int stride = gridDim.x * blockDim.x;
    for (int i = blockIdx.x * blockDim.x + threadIdx.x; i < n8; i += stride) {
        const float4* p = (const float4*)(in + (size_t)i * 8);
        float4 a = p[0], b = p[1];
        u16x8 o;
        o[0] = f2b(a.x); o[1] = f2b(a.y); o[2] = f2b(a.z); o[3] = f2b(a.w);
        o[4] = f2b(b.x); o[5] = f2b(b.y); o[6] = f2b(b.z); o[7] = f2b(b.w);
        *(u16x8*)(out + (size_t)i * 8) = o;
    }
}

// ---------------- kernel 2: QKV GEMM + phi/mask epilogue ----------------
// C[r][n] = sum_k X[r][k]*W[n][k] + bias[n];  q-part -> KQ (row-major bf16),
// k-part -> phi(c*mask) transposed into KKT[(b,h,d)][s], v-part -> VT[(b,h,m)][s]
__global__ __launch_bounds__(256) void gemm_qkv(
    const u16* __restrict__ Abf, const u16* __restrict__ Wbf,
    const float* __restrict__ bias, const float* __restrict__ mask,
    u16* __restrict__ KQ, u16* __restrict__ KKT, u16* __restrict__ VT)
{
    __shared__ __align__(16) u16 smem[16384];   // As 8192 | Bs 8192 (32 KB)
    u16* As = smem;
    u16* Bs = smem + 8192;

    int wg  = blockIdx.x;
    int swz = (wg & 7) * (3072 / 8) + (wg >> 3);   // XCD swizzle (3072 % 8 == 0)
    int tm = swz / 24, tn = swz % 24;
    int m0 = tm << 7, n0 = tn << 7;

    int t = threadIdx.x;
    int l = t & 63, w = t >> 6;
    int wr = w >> 1, wc = w & 1;
    int lg = l >> 4, lr = l & 15;

    f32x4 acc[4][4] = {};

    int srow = t >> 3;
    int scol = (t & 7) << 3;
    const u16* ga = Abf + (size_t)(m0 + srow) * K_ + scol;
    const u16* gb = Wbf + (size_t)(n0 + srow) * K_ + scol;
    u16* la = As + t * 8;
    u16* lb = Bs + t * 8;

    for (int kt = 0; kt < K_ / 64; ++kt) {
        __syncthreads();
        const u16* gak = ga + kt * 64;
        const u16* gbk = gb + kt * 64;
#pragma unroll
        for (int i = 0; i < 4; ++i) {
            gload16(gak + (size_t)i * 32 * K_, la + i * 2048);
            gload16(gbk + (size_t)i * 32 * K_, lb + i * 2048);
        }
        __syncthreads();
#pragma unroll
        for (int kh = 0; kh < 2; ++kh) {
            int ko = kh * 32 + lg * 8;
            bf16x8 af[4], bfr[4];
#pragma unroll
            for (int mi = 0; mi < 4; ++mi)
                af[mi] = *(const bf16x8*)&As[(wr * 64 + mi * 16 + lr) * 64 + ko];
#pragma unroll
            for (int ni = 0; ni < 4; ++ni)
                bfr[ni] = *(const bf16x8*)&Bs[(wc * 64 + ni * 16 + lr) * 64 + ko];
#pragma unroll
            for (int mi = 0; mi < 4; ++mi)
#pragma unroll
                for (int ni = 0; ni < 4; ++ni)
                    acc[mi][ni] = __builtin_amdgcn_mfma_f32_16x16x32_bf16(
                        af[mi], bfr[ni], acc[mi][ni], 0, 0, 0);
        }
    }

    int part = n0 >> 10;   // 0=q 1=k 2=v (tile never straddles: 128 | 1024)

    float bv[4];
#pragma unroll
    for (int ni = 0; ni < 4; ++ni) bv[ni] = bias[n0 + wc * 64 + ni * 16 + lr];

#pragma unroll
    for (int mi = 0; mi < 4; ++mi) {
#pragma unroll
        for (int j = 0; j < 4; ++j) {
            int row = m0 + wr * 64 + mi * 16 + lg * 4 + j;
            float mk = (part == 1) ? mask[row] : 1.f;
#pragma unroll
            for (int ni = 0; ni < 4; ++ni) {
                float v = acc[mi][ni][j] + bv[ni];
                if (part == 0)      v = phi_f(v);
                else if (part == 1) v = phi_f(v * mk);
                acc[mi][ni][j] = v;
            }
        }
    }

    if (part == 0) {
#pragma unroll
        for (int mi = 0; mi < 4; ++mi)
#pragma unroll
            for (int j = 0; j < 4; ++j) {
                int row = m0 + wr * 64 + mi * 16 + lg * 4 + j;
#pragma unroll
                for (int ni = 0; ni < 4; ++ni) {
                    int col = n0 + wc * 64 + ni * 16 + lr;
                    KQ[(size_t)row * E_ + col] = f2b(acc[mi][ni][j]);
                }
            }
    } else {
        u16* dst0 = (part == 1) ? KKT : VT;
        float* ldst = (float*)smem;    // [32][133] fp32 = 17 KB, aliases As/Bs
        int b  = m0 >> 12;
        int s0 = m0 & (S_ - 1);
#pragma unroll 1
        for (int p = 0; p < 4; ++p) {
            __syncthreads();
            if (wc == (p >> 1)) {
#pragma unroll
                for (int q = 0; q < 2; ++q) {
                    int ni = (p & 1) * 2 + q;
                    int nl = q * 16 + lr;
#pragma unroll
                    for (int mi = 0; mi < 4; ++mi)
#pragma unroll
                        for (int j = 0; j < 4; ++j) {
                            int rl = wr * 64 + mi * 16 + lg * 4 + j;
                            ldst[nl * 133 + rl] = acc[mi][ni][j];
                        }
                }
            }
            __syncthreads();
            int nl = t >> 3;
            int rseg = (t & 7) << 4;
            int cg = n0 + p * 32 + nl - (part << 10);   // 0..1023 within part
            int h = cg >> 6, d = cg & 63;
            u16* dst = dst0 + ((size_t)((b * H_ + h) * D_ + d)) * S_ + s0 + rseg;
            u16x8 o0, o1;
#pragma unroll
            for (int r = 0; r < 8; ++r) o0[r] = f2b(ldst[nl * 133 + rseg + r]);
#pragma unroll
            for (int r = 0; r < 8; ++r) o1[r] = f2b(ldst[nl * 133 + rseg + 8 + r]);
            *(u16x8*)dst = o0;
            *(u16x8*)(dst + 8) = o1;
        }
    }
}

// ---------------- kernel 3: kv + ksum partials over s-chunks ----------------
// per (bh, chunk): KVP[m][d] += sum_{s in chunk} v[s,m]*kk[s,d]; KSP[d] += sum kk
__global__ __launch_bounds__(256) void kv_ksum_partial(
    const u16* __restrict__ VT, const u16* __restrict__ KKT,
    float* __restrict__ KVP, float* __restrict__ KSP)
{
    __shared__ __align__(16) u16 smem[8192];   // As 4096 | Bs 4096
    u16* As = smem;
    u16* Bs = smem + 4096;
    int bh = blockIdx.x;
    int ch = blockIdx.y;
    int s0 = ch << 8;
    int t = threadIdx.x;
    int l = t & 63, w = t >> 6;
    int lg = l >> 4, lr = l & 15;
    const u16* Ag = VT + (size_t)bh * (D_ * S_);
    const u16* Bg = KKT + (size_t)bh * (D_ * S_);
    int srow = t >> 3, scol = (t & 7) << 3;

    f32x4 acc[4] = {};
    float ks = 0.f;
    int kd = t >> 2;
    int kq4 = (t & 3) << 4;

    for (int kt = 0; kt < 4; ++kt) {
        __syncthreads();
        int sb = s0 + kt * 64;
#pragma unroll
        for (int i = 0; i < 2; ++i) {
            gload16(Ag + (size_t)(srow + i * 32) * S_ + sb + scol, As + i * 2048 + t * 8);
            gload16(Bg + (size_t)(srow + i * 32) * S_ + sb + scol, Bs + i * 2048 + t * 8);
        }
        __syncthreads();
#pragma unroll
        for (int i = 0; i < 16; ++i) ks += b2f(Bs[kd * 64 + kq4 + i]);
#pragma unroll
        for (int kh = 0; kh < 2; ++kh) {
            int ko = kh * 32 + lg * 8;
            bf16x8 a = *(const bf16x8*)&As[(w * 16 + lr) * 64 + ko];
#pragma unroll
            for (int ni = 0; ni < 4; ++ni) {
                bf16x8 bb = *(const bf16x8*)&Bs[(ni * 16 + lr) * 64 + ko];
                acc[ni] = __builtin_amdgcn_mfma_f32_16x16x32_bf16(a, bb, acc[ni], 0, 0, 0);
            }
        }
    }
    float* kvp = KVP + (size_t)ch * (64 * 4096) + bh * 4096;
#pragma unroll
    for (int ni = 0; ni < 4; ++ni)
#pragma unroll
        for (int j = 0; j < 4; ++j)
            kvp[(w * 16 + lg * 4 + j) * 64 + ni * 16 + lr] = acc[ni][j];
    ks += __shfl_xor(ks, 1);
    ks += __shfl_xor(ks, 2);
    if ((t & 3) == 0) KSP[ch * 4096 + bh * 64 + kd] = ks;
}

// ---------------- kernel 4: deterministic partial reduce ----------------
__global__ void reduce_kv(const float* __restrict__ KVP, const float* __restrict__ KSP,
                          float* __restrict__ KV, float* __restrict__ KSUM)
{
    int g = blockIdx.x * 256 + threadIdx.x;   // 65536 threads
#pragma unroll 1
    for (int i = g * 4; i < g * 4 + 4; ++i) {
        float s = 0.f;
#pragma unroll
        for (int c = 0; c < 16; ++c) s += KVP[(size_t)c * (64 * 4096) + i];
        KV[i] = s;
    }
    if (g < 4096) {
        float s = 0.f;
#pragma unroll
        for (int c = 0; c < 16; ++c) s += KSP[c * 4096 + g];
        KSUM[g] = s;
    }
}

// ---------------- kernel 5: attn = kq·[kv;ksum] , divide by den ----------------
__global__ __launch_bounds__(256) void attn_out(
    const u16* __restrict__ KQ, const float* __restrict__ KV,
    const float* __restrict__ KSUM, float* __restrict__ Out)
{
    __shared__ __align__(16) u16 kqs[16384];   // 256 x 64 bf16 (32 KB)
    __shared__ __align__(16) u16 bsm[5120];    // 80 x 64 bf16 (rows 0-63 kv, 64 ksum, 65-79 zero)
    __shared__ float den[256];
    int bh = blockIdx.x, ch = blockIdx.y;
    int b = bh >> 4, h = bh & 15;
    int t = threadIdx.x;
    int l = t & 63, w = t >> 6;
    int lg = l >> 4, lr = l & 15;
    size_t row0 = (size_t)b * S_ + ch * 256;
    int srow = t >> 3, scol = (t & 7) << 3;
#pragma unroll
    for (int i = 0; i < 8; ++i)
        gload16(KQ + (row0 + srow + i * 32) * E_ + h * 64 + scol, kqs + i * 2048 + t * 8);

    const float* kvg = KV + bh * 4096;
#pragma unroll
    for (int ii = 0; ii < 16; ii += 4) {
        float4 v = *(const float4*)(kvg + t * 16 + ii);
        u16x4 o; o[0] = f2b(v.x); o[1] = f2b(v.y); o[2] = f2b(v.z); o[3] = f2b(v.w);
        *(u16x4*)&bsm[t * 16 + ii] = o;
    }
    if (t < 64) bsm[4096 + t] = f2b(KSUM[bh * 64 + t]);
    for (int i = t; i < 960; i += 256) bsm[4160 + i] = 0;
    __syncthreads();

    f32x4 acc[4][5] = {};
#pragma unroll
    for (int kh = 0; kh < 2; ++kh) {
        int ko = kh * 32 + lg * 8;
        bf16x8 af[4];
#pragma unroll
        for (int mi = 0; mi < 4; ++mi)
            af[mi] = *(const bf16x8*)&kqs[(w * 64 + mi * 16 + lr) * 64 + ko];
#pragma unroll
        for (int ni = 0; ni < 5; ++ni) {
            bf16x8 bb = *(const bf16x8*)&bsm[(ni * 16 + lr) * 64 + ko];
#pragma unroll
            for (int mi = 0; mi < 4; ++mi)
                acc[mi][ni] = __builtin_amdgcn_mfma_f32_16x16x32_bf16(af[mi], bb, acc[mi][ni], 0, 0, 0);
        }
    }
    if (lr == 0) {
#pragma unroll
        for (int mi = 0; mi < 4; ++mi)
#pragma unroll
            for (int j = 0; j < 4; ++j)
                den[w * 64 + mi * 16 + lg * 4 + j] = acc[mi][4][j];
    }
    __syncthreads();
#pragma unroll
    for (int mi = 0; mi < 4; ++mi)
#pragma unroll
        for (int j = 0; j < 4; ++j) {
            int sl = w * 64 + mi * 16 + lg * 4 + j;
            float z = 1.f / (den[sl] + 1e-6f);
            float* op = Out + (row0 + sl) * E_ + h * 64;
#pragma unroll
            for (int ni = 0; ni < 4; ++ni)
                op[ni * 16 + lr] = acc[mi][ni][j] * z;
        }
}

extern "C" void kernel_launch(void* const* d_in, const int* in_sizes, int n_in,
                              void* d_out, int out_size, void* d_ws, size_t ws_size,
                              hipStream_t stream)
{
    const float* inputs = (const float*)d_in[0];
    const float* mask   = (const float*)d_in[1];
    const float* w_qkv  = (const float*)d_in[2];
    const float* b_qkv  = (const float*)d_in[3];

    // workspace layout (~91.5 MB)
    u16* Abf = (u16*)d_ws;                      // 16777216 bf16
    u16* Wbf = Abf + (size_t)M_ * K_;           // 3145728 bf16
    u16* KQ  = Wbf + (size_t)N_ * K_;           // 16777216 bf16
    float* KVP  = (float*)(KQ + (size_t)M_ * E_);   // 16*262144 f32
    float* KSP  = KVP + 16 * 64 * 4096;             // 16*4096 f32
    float* KV   = KSP + 16 * 4096;                  // 262144 f32
    float* KSUM = KV + 64 * 4096;                   // 4096 f32

    // KK^T and V^T exactly fill d_out (2 x 33.55 MB); consumed before kernel 5
    // overwrites d_out with the final fp32 attention output.
    u16* KKT = (u16*)d_out;
    u16* VT  = KKT + (size_t)M_ * E_;

    cvt_bf16<<<2048, 256, 0, stream>>>(inputs, Abf, M_ * K_ / 8);
    cvt_bf16<<<768, 256, 0, stream>>>(w_qkv, Wbf, N_ * K_ / 8);
    gemm_qkv<<<3072, 256, 0, stream>>>(Abf, Wbf, b_qkv, mask, KQ, KKT, VT);
    kv_ksum_partial<<<dim3(64, 16), 256, 0, stream>>>(VT, KKT, KVP, KSP);
    reduce_kv<<<256, 256, 0, stream>>>(KVP, KSP, KV, KSUM);
    attn_out<<<dim3(64, 16), 256, 0, stream>>>(KQ, KV, KSUM, (float*)d_out);
}

// Round 2
// 199.938 us; speedup vs baseline: 6.1626x; 6.1626x over previous
//
#include <hip/hip_runtime.h>

typedef unsigned short u16;
typedef short bf16x8 __attribute__((ext_vector_type(8)));
typedef float f32x4 __attribute__((ext_vector_type(4)));
typedef u16 u16x8 __attribute__((ext_vector_type(8)));
typedef u16 u16x4 __attribute__((ext_vector_type(4)));

#define B_ 4
#define S_ 4096
#define E_ 1024
#define H_ 16
#define D_ 64
#define M_ 16384
#define N_ 3072
#define K_ 1024

__device__ __forceinline__ u16 f2b(float f) {
    unsigned x = __builtin_bit_cast(unsigned, f);
    return (u16)((x + 0x7fffu + ((x >> 16) & 1u)) >> 16);   // RNE
}
__device__ __forceinline__ float b2f(u16 u) {
    unsigned x = ((unsigned)u) << 16;
    return __builtin_bit_cast(float, x);
}
__device__ __forceinline__ float phi_f(float x) { return x > 0.f ? x + 1.f : __expf(x); }

__device__ __forceinline__ void gload16(const void* g, void* l) {
    __builtin_amdgcn_global_load_lds((const __attribute__((address_space(1))) void*)g,
                                     (__attribute__((address_space(3))) void*)l, 16, 0, 0);
}

// ---------------- kernel 1: fp32 -> bf16 convert ----------------
__global__ void cvt_bf16(const float* __restrict__ in, u16* __restrict__ out, int n8) {
    int stride = gridDim.x * blockDim.x;
    for (int i = blockIdx.x * blockDim.x + threadIdx.x; i < n8; i += stride) {
        const float4* p = (const float4*)(in + (size_t)i * 8);
        float4 a = p[0], b = p[1];
        u16x8 o;
        o[0] = f2b(a.x); o[1] = f2b(a.y); o[2] = f2b(a.z); o[3] = f2b(a.w);
        o[4] = f2b(b.x); o[5] = f2b(b.y); o[6] = f2b(b.z); o[7] = f2b(b.w);
        *(u16x8*)(out + (size_t)i * 8) = o;
    }
}

// ---------------- kernel 2: QKV GEMM + phi/mask epilogue ----------------
// C[r][n] = sum_k X[r][k]*W[n][k] + bias[n];  q-part -> KQ (row-major bf16),
// k-part -> phi(c*mask) transposed into KKT[(b,h,d)][s], v-part -> VT[(b,h,m)][s]
__global__ __launch_bounds__(256) void gemm_qkv(
    const u16* __restrict__ Abf, const u16* __restrict__ Wbf,
    const float* __restrict__ bias, const float* __restrict__ mask,
    u16* __restrict__ KQ, u16* __restrict__ KKT, u16* __restrict__ VT)
{
    __shared__ __align__(16) u16 smem[16384];   // As 8192 | Bs 8192 (32 KB)
    u16* As = smem;
    u16* Bs = smem + 8192;

    // Tile order: each XCD owns a 16-row strip of M-tiles; within the strip,
    // 8x8 tile super-groups (A-panels 2MB + B-panels 2MB fit 4MB L2).
    int wg  = blockIdx.x;
    int xcd = wg & 7;
    int idx = wg >> 3;            // 0..383 per XCD
    int gc  = idx >> 6;           // 0..5  (6 groups of 64 tiles)
    int w8  = idx & 63;
    int tm  = xcd * 16 + (gc & 1) * 8 + (w8 & 7);
    int tn  = (gc >> 1) * 8 + (w8 >> 3);
    int m0 = tm << 7, n0 = tn << 7;

    int t = threadIdx.x;
    int l = t & 63, w = t >> 6;
    int wr = w >> 1, wc = w & 1;
    int lg = l >> 4, lr = l & 15;

    f32x4 acc[4][4] = {};

    int srow = t >> 3;
    int scol = (t & 7) << 3;
    const u16* ga = Abf + (size_t)(m0 + srow) * K_ + scol;
    const u16* gb = Wbf + (size_t)(n0 + srow) * K_ + scol;
    u16* la = As + t * 8;
    u16* lb = Bs + t * 8;

    for (int kt = 0; kt < K_ / 64; ++kt) {
        __syncthreads();
        const u16* gak = ga + kt * 64;
        const u16* gbk = gb + kt * 64;
#pragma unroll
        for (int i = 0; i < 4; ++i) {
            gload16(gak + (size_t)i * 32 * K_, la + i * 2048);
            gload16(gbk + (size_t)i * 32 * K_, lb + i * 2048);
        }
        __syncthreads();
#pragma unroll
        for (int kh = 0; kh < 2; ++kh) {
            int ko = kh * 32 + lg * 8;
            bf16x8 af[4], bfr[4];
#pragma unroll
            for (int mi = 0; mi < 4; ++mi)
                af[mi] = *(const bf16x8*)&As[(wr * 64 + mi * 16 + lr) * 64 + ko];
#pragma unroll
            for (int ni = 0; ni < 4; ++ni)
                bfr[ni] = *(const bf16x8*)&Bs[(wc * 64 + ni * 16 + lr) * 64 + ko];
#pragma unroll
            for (int mi = 0; mi < 4; ++mi)
#pragma unroll
                for (int ni = 0; ni < 4; ++ni)
                    acc[mi][ni] = __builtin_amdgcn_mfma_f32_16x16x32_bf16(
                        af[mi], bfr[ni], acc[mi][ni], 0, 0, 0);
        }
    }

    int part = n0 >> 10;   // 0=q 1=k 2=v (tile never straddles: 128 | 1024)

    float bv[4];
#pragma unroll
    for (int ni = 0; ni < 4; ++ni) bv[ni] = bias[n0 + wc * 64 + ni * 16 + lr];

#pragma unroll
    for (int mi = 0; mi < 4; ++mi) {
#pragma unroll
        for (int j = 0; j < 4; ++j) {
            int row = m0 + wr * 64 + mi * 16 + lg * 4 + j;
            float mk = (part == 1) ? mask[row] : 1.f;
#pragma unroll
            for (int ni = 0; ni < 4; ++ni) {
                float v = acc[mi][ni][j] + bv[ni];
                if (part == 0)      v = phi_f(v);
                else if (part == 1) v = phi_f(v * mk);
                acc[mi][ni][j] = v;
            }
        }
    }

    if (part == 0) {
#pragma unroll
        for (int mi = 0; mi < 4; ++mi)
#pragma unroll
            for (int j = 0; j < 4; ++j) {
                int row = m0 + wr * 64 + mi * 16 + lg * 4 + j;
#pragma unroll
                for (int ni = 0; ni < 4; ++ni) {
                    int col = n0 + wc * 64 + ni * 16 + lr;
                    KQ[(size_t)row * E_ + col] = f2b(acc[mi][ni][j]);
                }
            }
    } else {
        u16* dst0 = (part == 1) ? KKT : VT;
        float* ldst = (float*)smem;    // [32][133] fp32 = 17 KB, aliases As/Bs
        int b  = m0 >> 12;
        int s0 = m0 & (S_ - 1);
        // FULLY unrolled: p must be compile-time so acc[][] indexing stays
        // static (runtime index -> whole acc array in scratch; R0->R1 lesson:
        // 5.26 GB scratch write traffic, VGPR 76, MfmaUtil 3.4%).
#pragma unroll
        for (int p = 0; p < 4; ++p) {
            __syncthreads();
            if (wc == (p >> 1)) {
#pragma unroll
                for (int q = 0; q < 2; ++q) {
                    int ni = (p & 1) * 2 + q;
                    int nl = q * 16 + lr;
#pragma unroll
                    for (int mi = 0; mi < 4; ++mi)
#pragma unroll
                        for (int j = 0; j < 4; ++j) {
                            int rl = wr * 64 + mi * 16 + lg * 4 + j;
                            ldst[nl * 133 + rl] = acc[mi][ni][j];
                        }
                }
            }
            __syncthreads();
            int nl = t >> 3;
            int rseg = (t & 7) << 4;
            int cg = n0 + p * 32 + nl - (part << 10);   // 0..1023 within part
            int h = cg >> 6, d = cg & 63;
            u16* dst = dst0 + ((size_t)((b * H_ + h) * D_ + d)) * S_ + s0 + rseg;
            u16x8 o0, o1;
#pragma unroll
            for (int r = 0; r < 8; ++r) o0[r] = f2b(ldst[nl * 133 + rseg + r]);
#pragma unroll
            for (int r = 0; r < 8; ++r) o1[r] = f2b(ldst[nl * 133 + rseg + 8 + r]);
            *(u16x8*)dst = o0;
            *(u16x8*)(dst + 8) = o1;
        }
    }
}

// ---------------- kernel 3: kv + ksum partials over s-chunks ----------------
// per (bh, chunk): KVP[m][d] += sum_{s in chunk} v[s,m]*kk[s,d]; KSP[d] += sum kk
__global__ __launch_bounds__(256) void kv_ksum_partial(
    const u16* __restrict__ VT, const u16* __restrict__ KKT,
    float* __restrict__ KVP, float* __restrict__ KSP)
{
    __shared__ __align__(16) u16 smem[8192];   // As 4096 | Bs 4096
    u16* As = smem;
    u16* Bs = smem + 4096;
    int bh = blockIdx.x;
    int ch = blockIdx.y;
    int s0 = ch << 8;
    int t = threadIdx.x;
    int l = t & 63, w = t >> 6;
    int lg = l >> 4, lr = l & 15;
    const u16* Ag = VT + (size_t)bh * (D_ * S_);
    const u16* Bg = KKT + (size_t)bh * (D_ * S_);
    int srow = t >> 3, scol = (t & 7) << 3;

    f32x4 acc[4] = {};
    float ks = 0.f;
    int kd = t >> 2;
    int kq4 = (t & 3) << 4;

    for (int kt = 0; kt < 4; ++kt) {
        __syncthreads();
        int sb = s0 + kt * 64;
#pragma unroll
        for (int i = 0; i < 2; ++i) {
            gload16(Ag + (size_t)(srow + i * 32) * S_ + sb + scol, As + i * 2048 + t * 8);
            gload16(Bg + (size_t)(srow + i * 32) * S_ + sb + scol, Bs + i * 2048 + t * 8);
        }
        __syncthreads();
#pragma unroll
        for (int i = 0; i < 16; ++i) ks += b2f(Bs[kd * 64 + kq4 + i]);
#pragma unroll
        for (int kh = 0; kh < 2; ++kh) {
            int ko = kh * 32 + lg * 8;
            bf16x8 a = *(const bf16x8*)&As[(w * 16 + lr) * 64 + ko];
#pragma unroll
            for (int ni = 0; ni < 4; ++ni) {
                bf16x8 bb = *(const bf16x8*)&Bs[(ni * 16 + lr) * 64 + ko];
                acc[ni] = __builtin_amdgcn_mfma_f32_16x16x32_bf16(a, bb, acc[ni], 0, 0, 0);
            }
        }
    }
    float* kvp = KVP + (size_t)ch * (64 * 4096) + bh * 4096;
#pragma unroll
    for (int ni = 0; ni < 4; ++ni)
#pragma unroll
        for (int j = 0; j < 4; ++j)
            kvp[(w * 16 + lg * 4 + j) * 64 + ni * 16 + lr] = acc[ni][j];
    ks += __shfl_xor(ks, 1);
    ks += __shfl_xor(ks, 2);
    if ((t & 3) == 0) KSP[ch * 4096 + bh * 64 + kd] = ks;
}

// ---------------- kernel 4: deterministic partial reduce ----------------
__global__ void reduce_kv(const float* __restrict__ KVP, const float* __restrict__ KSP,
                          float* __restrict__ KV, float* __restrict__ KSUM)
{
    int g = blockIdx.x * 256 + threadIdx.x;   // 65536 threads
#pragma unroll 1
    for (int i = g * 4; i < g * 4 + 4; ++i) {
        float s = 0.f;
#pragma unroll
        for (int c = 0; c < 16; ++c) s += KVP[(size_t)c * (64 * 4096) + i];
        KV[i] = s;
    }
    if (g < 4096) {
        float s = 0.f;
#pragma unroll
        for (int c = 0; c < 16; ++c) s += KSP[c * 4096 + g];
        KSUM[g] = s;
    }
}

// ---------------- kernel 5: attn = kq·[kv;ksum] , divide by den ----------------
__global__ __launch_bounds__(256) void attn_out(
    const u16* __restrict__ KQ, const float* __restrict__ KV,
    const float* __restrict__ KSUM, float* __restrict__ Out)
{
    __shared__ __align__(16) u16 kqs[16384];   // 256 x 64 bf16 (32 KB)
    __shared__ __align__(16) u16 bsm[5120];    // 80 x 64 bf16 (rows 0-63 kv, 64 ksum, 65-79 zero)
    __shared__ float den[256];
    int bh = blockIdx.x, ch = blockIdx.y;
    int b = bh >> 4, h = bh & 15;
    int t = threadIdx.x;
    int l = t & 63, w = t >> 6;
    int lg = l >> 4, lr = l & 15;
    size_t row0 = (size_t)b * S_ + ch * 256;
    int srow = t >> 3, scol = (t & 7) << 3;
#pragma unroll
    for (int i = 0; i < 8; ++i)
        gload16(KQ + (row0 + srow + i * 32) * E_ + h * 64 + scol, kqs + i * 2048 + t * 8);

    const float* kvg = KV + bh * 4096;
#pragma unroll
    for (int ii = 0; ii < 16; ii += 4) {
        float4 v = *(const float4*)(kvg + t * 16 + ii);
        u16x4 o; o[0] = f2b(v.x); o[1] = f2b(v.y); o[2] = f2b(v.z); o[3] = f2b(v.w);
        *(u16x4*)&bsm[t * 16 + ii] = o;
    }
    if (t < 64) bsm[4096 + t] = f2b(KSUM[bh * 64 + t]);
    for (int i = t; i < 960; i += 256) bsm[4160 + i] = 0;
    __syncthreads();

    f32x4 acc[4][5] = {};
#pragma unroll
    for (int kh = 0; kh < 2; ++kh) {
        int ko = kh * 32 + lg * 8;
        bf16x8 af[4];
#pragma unroll
        for (int mi = 0; mi < 4; ++mi)
            af[mi] = *(const bf16x8*)&kqs[(w * 64 + mi * 16 + lr) * 64 + ko];
#pragma unroll
        for (int ni = 0; ni < 5; ++ni) {
            bf16x8 bb = *(const bf16x8*)&bsm[(ni * 16 + lr) * 64 + ko];
#pragma unroll
            for (int mi = 0; mi < 4; ++mi)
                acc[mi][ni] = __builtin_amdgcn_mfma_f32_16x16x32_bf16(af[mi], bb, acc[mi][ni], 0, 0, 0);
        }
    }
    if (lr == 0) {
#pragma unroll
        for (int mi = 0; mi < 4; ++mi)
#pragma unroll
            for (int j = 0; j < 4; ++j)
                den[w * 64 + mi * 16 + lg * 4 + j] = acc[mi][4][j];
    }
    __syncthreads();
#pragma unroll
    for (int mi = 0; mi < 4; ++mi)
#pragma unroll
        for (int j = 0; j < 4; ++j) {
            int sl = w * 64 + mi * 16 + lg * 4 + j;
            float z = 1.f / (den[sl] + 1e-6f);
            float* op = Out + (row0 + sl) * E_ + h * 64;
#pragma unroll
            for (int ni = 0; ni < 4; ++ni)
                op[ni * 16 + lr] = acc[mi][ni][j] * z;
        }
}

extern "C" void kernel_launch(void* const* d_in, const int* in_sizes, int n_in,
                              void* d_out, int out_size, void* d_ws, size_t ws_size,
                              hipStream_t stream)
{
    const float* inputs = (const float*)d_in[0];
    const float* mask   = (const float*)d_in[1];
    const float* w_qkv  = (const float*)d_in[2];
    const float* b_qkv  = (const float*)d_in[3];

    // workspace layout (~91.5 MB)
    u16* Abf = (u16*)d_ws;                      // 16777216 bf16
    u16* Wbf = Abf + (size_t)M_ * K_;           // 3145728 bf16
    u16* KQ  = Wbf + (size_t)N_ * K_;           // 16777216 bf16
    float* KVP  = (float*)(KQ + (size_t)M_ * E_);   // 16*262144 f32
    float* KSP  = KVP + 16 * 64 * 4096;             // 16*4096 f32
    float* KV   = KSP + 16 * 4096;                  // 262144 f32
    float* KSUM = KV + 64 * 4096;                   // 4096 f32

    // KK^T and V^T exactly fill d_out (2 x 33.55 MB); consumed before kernel 5
    // overwrites d_out with the final fp32 attention output.
    u16* KKT = (u16*)d_out;
    u16* VT  = KKT + (size_t)M_ * E_;

    cvt_bf16<<<2048, 256, 0, stream>>>(inputs, Abf, M_ * K_ / 8);
    cvt_bf16<<<768, 256, 0, stream>>>(w_qkv, Wbf, N_ * K_ / 8);
    gemm_qkv<<<3072, 256, 0, stream>>>(Abf, Wbf, b_qkv, mask, KQ, KKT, VT);
    kv_ksum_partial<<<dim3(64, 16), 256, 0, stream>>>(VT, KKT, KVP, KSP);
    reduce_kv<<<256, 256, 0, stream>>>(KVP, KSP, KV, KSUM);
    attn_out<<<dim3(64, 16), 256, 0, stream>>>(KQ, KV, KSUM, (float*)d_out);
}

// Round 3
// 168.552 us; speedup vs baseline: 7.3101x; 1.1862x over previous
//
#include <hip/hip_runtime.h>

typedef unsigned short u16;
typedef short bf16x8 __attribute__((ext_vector_type(8)));
typedef float f32x4 __attribute__((ext_vector_type(4)));
typedef u16 u16x8 __attribute__((ext_vector_type(8)));
typedef u16 u16x4 __attribute__((ext_vector_type(4)));

#define B_ 4
#define S_ 4096
#define E_ 1024
#define H_ 16
#define D_ 64
#define M_ 16384
#define N_ 3072
#define K_ 1024

__device__ __forceinline__ u16 f2b(float f) {
    unsigned x = __builtin_bit_cast(unsigned, f);
    return (u16)((x + 0x7fffu + ((x >> 16) & 1u)) >> 16);   // RNE
}
__device__ __forceinline__ float b2f(u16 u) {
    unsigned x = ((unsigned)u) << 16;
    return __builtin_bit_cast(float, x);
}
__device__ __forceinline__ float phi_f(float x) { return x > 0.f ? x + 1.f : __expf(x); }

__device__ __forceinline__ void gload16(const void* g, void* l) {
    __builtin_amdgcn_global_load_lds((const __attribute__((address_space(1))) void*)g,
                                     (__attribute__((address_space(3))) void*)l, 16, 0, 0);
}

// ---------------- kernel 1: fp32 -> bf16 convert ----------------
__global__ void cvt_bf16(const float* __restrict__ in, u16* __restrict__ out, int n8) {
    int stride = gridDim.x * blockDim.x;
    for (int i = blockIdx.x * blockDim.x + threadIdx.x; i < n8; i += stride) {
        const float4* p = (const float4*)(in + (size_t)i * 8);
        float4 a = p[0], b = p[1];
        u16x8 o;
        o[0] = f2b(a.x); o[1] = f2b(a.y); o[2] = f2b(a.z); o[3] = f2b(a.w);
        o[4] = f2b(b.x); o[5] = f2b(b.y); o[6] = f2b(b.z); o[7] = f2b(b.w);
        *(u16x8*)(out + (size_t)i * 8) = o;
    }
}

// ---------------- kernel 2: QKV GEMM, 256^2 tile, deep pipeline ----------------
// Structure: double-buffered 128KB LDS, counted vmcnt(8) (T4), XOR-swizzled LDS
// via pre-swizzled global source (T2/m173), setprio around MFMA clusters (T5).
// Race rules: (1) a buffer is re-staged only after the barrier following its
// last reader phase; (2) a buffer is read only after every wave did
// vmcnt(<=8) covering that buffer's loads, followed by a barrier.

__device__ __forceinline__ void compute_tile(const char* ldsbase, int rowA, int rowB,
                                             int pc0, int pc1, f32x4 (&acc)[8][4])
{
    const char* bA = ldsbase + rowA;
    const char* bB = ldsbase + 32768 + rowB;
#pragma unroll
    for (int kk = 0; kk < 2; ++kk) {
        int pc = kk ? pc1 : pc0;
        bf16x8 a[8], bb[4];
#pragma unroll
        for (int mi = 0; mi < 8; ++mi) a[mi] = *(const bf16x8*)(bA + mi * 2048 + pc);
#pragma unroll
        for (int ni = 0; ni < 4; ++ni) bb[ni] = *(const bf16x8*)(bB + ni * 2048 + pc);
        __builtin_amdgcn_s_setprio(1);
#pragma unroll
        for (int mi = 0; mi < 8; ++mi)
#pragma unroll
            for (int ni = 0; ni < 4; ++ni)
                acc[mi][ni] = __builtin_amdgcn_mfma_f32_16x16x32_bf16(
                    a[mi], bb[ni], acc[mi][ni], 0, 0, 0);
        __builtin_amdgcn_s_setprio(0);
    }
}

__device__ __forceinline__ void stage_tile(const u16* gA, const u16* gB, char* ldsbase, int t)
{
#pragma unroll
    for (int i = 0; i < 4; ++i)
        gload16(gA + (size_t)i * 64 * K_, ldsbase + i * 8192 + t * 16);
#pragma unroll
    for (int i = 0; i < 4; ++i)
        gload16(gB + (size_t)i * 64 * K_, ldsbase + 32768 + i * 8192 + t * 16);
}

#define MEMFENCE asm volatile("" ::: "memory")

__global__ __launch_bounds__(512, 2) void gemm_qkv(
    const u16* __restrict__ Abf, const u16* __restrict__ Wbf,
    const float* __restrict__ bias, const float* __restrict__ mask,
    u16* __restrict__ KQ, u16* __restrict__ KKT, u16* __restrict__ VT)
{
    __shared__ __align__(16) char lds[131072];   // A0|B0|A1|B1 = 4 x 32KB

    int wg  = blockIdx.x;
    int xcd = wg & 7, ii = wg >> 3;        // 768 % 8 == 0 -> bijective
    int tm  = xcd * 8 + ii / 12;           // per-XCD: n-fastest (A-panel stays L2-hot)
    int tn  = ii % 12;
    int m0 = tm << 8, n0 = tn << 8;

    int t = threadIdx.x;
    int l = t & 63, wid = t >> 6;
    int wr = wid >> 2, wc = wid & 3;       // 2 x 4 waves, per-wave C = 128x64
    int lg = l >> 4, lr = l & 15;

    // staging: lane covers LDS bytes [t*16, t*16+16) of a half-row; the global
    // source col is pre-swizzled so LDS holds physcol = logcol ^ ((row&7)<<4)
    int srow  = t >> 3;                    // 0..63
    int scolE = ((t & 7) ^ (srow & 7)) << 3;
    const u16* gA = Abf + (size_t)(m0 + srow) * K_ + scolE;
    const u16* gB = Wbf + (size_t)(n0 + srow) * K_ + scolE;

    // read-side swizzle
    int rowA = (wr * 128 + lr) * 128;
    int rowB = (wc * 64 + lr) * 128;
    int pc0  = (lg * 16) ^ ((lr & 7) << 4);
    int pc1  = pc0 ^ 64;

    f32x4 acc[8][4] = {};

    stage_tile(gA, gB, lds, t);            // tile 0 -> buf0
    stage_tile(gA + 64, gB + 64, lds + 65536, t);  // tile 1 -> buf1
    asm volatile("s_waitcnt vmcnt(8)" ::: "memory"); // tile0 landed (FIFO)
    __builtin_amdgcn_s_barrier();
    MEMFENCE;

    for (int kt2 = 0; kt2 < 14; kt2 += 2) {
        // ---- even tile kt2 from buf0 ----
        compute_tile(lds, rowA, rowB, pc0, pc1, acc);
        MEMFENCE;
        __builtin_amdgcn_s_barrier();      // all reads of buf0 done chip-wide
        MEMFENCE;
        stage_tile(gA + (size_t)(kt2 + 2) * 64, gB + (size_t)(kt2 + 2) * 64, lds, t);
        asm volatile("s_waitcnt vmcnt(8)" ::: "memory"); // tile kt2+1 landed
        __builtin_amdgcn_s_barrier();
        MEMFENCE;
        // ---- odd tile kt2+1 from buf1 ----
        compute_tile(lds + 65536, rowA, rowB, pc0, pc1, acc);
        MEMFENCE;
        __builtin_amdgcn_s_barrier();
        MEMFENCE;
        stage_tile(gA + (size_t)(kt2 + 3) * 64, gB + (size_t)(kt2 + 3) * 64, lds + 65536, t);
        asm volatile("s_waitcnt vmcnt(8)" ::: "memory"); // tile kt2+2 landed
        __builtin_amdgcn_s_barrier();
        MEMFENCE;
    }
    compute_tile(lds, rowA, rowB, pc0, pc1, acc);            // tile 14
    asm volatile("s_waitcnt vmcnt(0)" ::: "memory");         // drain tile 15
    __builtin_amdgcn_s_barrier();
    MEMFENCE;
    compute_tile(lds + 65536, rowA, rowB, pc0, pc1, acc);    // tile 15

    // ---------------- epilogue: bias + phi/mask + store ----------------
    int part = n0 >> 10;   // 0=q 1=k 2=v (BN=256 divides the 1024 parts)

    float bv[4];
#pragma unroll
    for (int ni = 0; ni < 4; ++ni) bv[ni] = bias[n0 + wc * 64 + ni * 16 + lr];

    if (part == 0) {
#pragma unroll
        for (int mi = 0; mi < 8; ++mi)
#pragma unroll
            for (int j = 0; j < 4; ++j) {
                int row = m0 + wr * 128 + mi * 16 + lg * 4 + j;
#pragma unroll
                for (int ni = 0; ni < 4; ++ni) {
                    int col = n0 + wc * 64 + ni * 16 + lr;
                    KQ[(size_t)row * E_ + col] = f2b(phi_f(acc[mi][ni][j] + bv[ni]));
                }
            }
    } else {
        u16* dst0 = (part == 1) ? KKT : VT;
        int b  = m0 >> 12;
        int sl = m0 & (S_ - 1);
        int h  = ((tn & 3) << 2) | wc;     // this wave's 64-col block = one head
#pragma unroll
        for (int mi = 0; mi < 8; ++mi) {
            int sbase = sl + wr * 128 + mi * 16 + lg * 4;
            float mk[4];
#pragma unroll
            for (int j = 0; j < 4; ++j)
                mk[j] = (part == 1) ? mask[m0 + wr * 128 + mi * 16 + lg * 4 + j] : 1.f;
#pragma unroll
            for (int ni = 0; ni < 4; ++ni) {
                u16x4 o;
#pragma unroll
                for (int j = 0; j < 4; ++j) {
                    float v = acc[mi][ni][j] + bv[ni];
                    if (part == 1) v = phi_f(v * mk[j]);
                    o[j] = f2b(v);
                }
                int d = ni * 16 + lr;
                *(u16x4*)(dst0 + ((size_t)((b * H_ + h) * D_ + d)) * S_ + sbase) = o;
            }
        }
    }
}

// ---------------- kernel 3: kv + ksum partials over s-chunks ----------------
__global__ __launch_bounds__(256) void kv_ksum_partial(
    const u16* __restrict__ VT, const u16* __restrict__ KKT,
    float* __restrict__ KVP, float* __restrict__ KSP)
{
    __shared__ __align__(16) u16 smem[8192];   // As 4096 | Bs 4096
    u16* As = smem;
    u16* Bs = smem + 4096;
    int bh = blockIdx.x;
    int ch = blockIdx.y;
    int s0 = ch << 8;
    int t = threadIdx.x;
    int l = t & 63, w = t >> 6;
    int lg = l >> 4, lr = l & 15;
    const u16* Ag = VT + (size_t)bh * (D_ * S_);
    const u16* Bg = KKT + (size_t)bh * (D_ * S_);
    int srow = t >> 3, scol = (t & 7) << 3;

    f32x4 acc[4] = {};
    float ks = 0.f;
    int kd = t >> 2;
    int kq4 = (t & 3) << 4;

    for (int kt = 0; kt < 4; ++kt) {
        __syncthreads();
        int sb = s0 + kt * 64;
#pragma unroll
        for (int i = 0; i < 2; ++i) {
            gload16(Ag + (size_t)(srow + i * 32) * S_ + sb + scol, As + i * 2048 + t * 8);
            gload16(Bg + (size_t)(srow + i * 32) * S_ + sb + scol, Bs + i * 2048 + t * 8);
        }
        __syncthreads();
#pragma unroll
        for (int i = 0; i < 16; ++i) ks += b2f(Bs[kd * 64 + kq4 + i]);
#pragma unroll
        for (int kh = 0; kh < 2; ++kh) {
            int ko = kh * 32 + lg * 8;
            bf16x8 a = *(const bf16x8*)&As[(w * 16 + lr) * 64 + ko];
#pragma unroll
            for (int ni = 0; ni < 4; ++ni) {
                bf16x8 bb = *(const bf16x8*)&Bs[(ni * 16 + lr) * 64 + ko];
                acc[ni] = __builtin_amdgcn_mfma_f32_16x16x32_bf16(a, bb, acc[ni], 0, 0, 0);
            }
        }
    }
    float* kvp = KVP + (size_t)ch * (64 * 4096) + bh * 4096;
#pragma unroll
    for (int ni = 0; ni < 4; ++ni)
#pragma unroll
        for (int j = 0; j < 4; ++j)
            kvp[(w * 16 + lg * 4 + j) * 64 + ni * 16 + lr] = acc[ni][j];
    ks += __shfl_xor(ks, 1);
    ks += __shfl_xor(ks, 2);
    if ((t & 3) == 0) KSP[ch * 4096 + bh * 64 + kd] = ks;
}

// ---------------- kernel 4: deterministic partial reduce ----------------
__global__ void reduce_kv(const float* __restrict__ KVP, const float* __restrict__ KSP,
                          float* __restrict__ KV, float* __restrict__ KSUM)
{
    int g = blockIdx.x * 256 + threadIdx.x;   // 65536 threads
#pragma unroll 1
    for (int i = g * 4; i < g * 4 + 4; ++i) {
        float s = 0.f;
#pragma unroll
        for (int c = 0; c < 16; ++c) s += KVP[(size_t)c * (64 * 4096) + i];
        KV[i] = s;
    }
    if (g < 4096) {
        float s = 0.f;
#pragma unroll
        for (int c = 0; c < 16; ++c) s += KSP[c * 4096 + g];
        KSUM[g] = s;
    }
}

// ---------------- kernel 5: attn = kq·[kv;ksum] , divide by den ----------------
__global__ __launch_bounds__(256) void attn_out(
    const u16* __restrict__ KQ, const float* __restrict__ KV,
    const float* __restrict__ KSUM, float* __restrict__ Out)
{
    __shared__ __align__(16) u16 kqs[16384];   // 256 x 64 bf16 (32 KB)
    __shared__ __align__(16) u16 bsm[5120];    // 80 x 64 bf16 (rows 0-63 kv, 64 ksum, 65-79 zero)
    __shared__ float den[256];
    int bh = blockIdx.x, ch = blockIdx.y;
    int b = bh >> 4, h = bh & 15;
    int t = threadIdx.x;
    int l = t & 63, w = t >> 6;
    int lg = l >> 4, lr = l & 15;
    size_t row0 = (size_t)b * S_ + ch * 256;
    int srow = t >> 3, scol = (t & 7) << 3;
#pragma unroll
    for (int i = 0; i < 8; ++i)
        gload16(KQ + (row0 + srow + i * 32) * E_ + h * 64 + scol, kqs + i * 2048 + t * 8);

    const float* kvg = KV + bh * 4096;
#pragma unroll
    for (int ii = 0; ii < 16; ii += 4) {
        float4 v = *(const float4*)(kvg + t * 16 + ii);
        u16x4 o; o[0] = f2b(v.x); o[1] = f2b(v.y); o[2] = f2b(v.z); o[3] = f2b(v.w);
        *(u16x4*)&bsm[t * 16 + ii] = o;
    }
    if (t < 64) bsm[4096 + t] = f2b(KSUM[bh * 64 + t]);
    for (int i = t; i < 960; i += 256) bsm[4160 + i] = 0;
    __syncthreads();

    f32x4 acc[4][5] = {};
#pragma unroll
    for (int kh = 0; kh < 2; ++kh) {
        int ko = kh * 32 + lg * 8;
        bf16x8 af[4];
#pragma unroll
        for (int mi = 0; mi < 4; ++mi)
            af[mi] = *(const bf16x8*)&kqs[(w * 64 + mi * 16 + lr) * 64 + ko];
#pragma unroll
        for (int ni = 0; ni < 5; ++ni) {
            bf16x8 bb = *(const bf16x8*)&bsm[(ni * 16 + lr) * 64 + ko];
#pragma unroll
            for (int mi = 0; mi < 4; ++mi)
                acc[mi][ni] = __builtin_amdgcn_mfma_f32_16x16x32_bf16(af[mi], bb, acc[mi][ni], 0, 0, 0);
        }
    }
    if (lr == 0) {
#pragma unroll
        for (int mi = 0; mi < 4; ++mi)
#pragma unroll
            for (int j = 0; j < 4; ++j)
                den[w * 64 + mi * 16 + lg * 4 + j] = acc[mi][4][j];
    }
    __syncthreads();
#pragma unroll
    for (int mi = 0; mi < 4; ++mi)
#pragma unroll
        for (int j = 0; j < 4; ++j) {
            int sl = w * 64 + mi * 16 + lg * 4 + j;
            float z = 1.f / (den[sl] + 1e-6f);
            float* op = Out + (row0 + sl) * E_ + h * 64;
#pragma unroll
            for (int ni = 0; ni < 4; ++ni)
                op[ni * 16 + lr] = acc[mi][ni][j] * z;
        }
}

extern "C" void kernel_launch(void* const* d_in, const int* in_sizes, int n_in,
                              void* d_out, int out_size, void* d_ws, size_t ws_size,
                              hipStream_t stream)
{
    const float* inputs = (const float*)d_in[0];
    const float* mask   = (const float*)d_in[1];
    const float* w_qkv  = (const float*)d_in[2];
    const float* b_qkv  = (const float*)d_in[3];

    // workspace layout (~91.5 MB)
    u16* Abf = (u16*)d_ws;                      // 16777216 bf16
    u16* Wbf = Abf + (size_t)M_ * K_;           // 3145728 bf16
    u16* KQ  = Wbf + (size_t)N_ * K_;           // 16777216 bf16
    float* KVP  = (float*)(KQ + (size_t)M_ * E_);   // 16*262144 f32
    float* KSP  = KVP + 16 * 64 * 4096;             // 16*4096 f32
    float* KV   = KSP + 16 * 4096;                  // 262144 f32
    float* KSUM = KV + 64 * 4096;                   // 4096 f32

    // KK^T and V^T exactly fill d_out (2 x 33.55 MB); consumed before kernel 5
    // overwrites d_out with the final fp32 attention output.
    u16* KKT = (u16*)d_out;
    u16* VT  = KKT + (size_t)M_ * E_;

    cvt_bf16<<<2048, 256, 0, stream>>>(inputs, Abf, M_ * K_ / 8);
    cvt_bf16<<<768, 256, 0, stream>>>(w_qkv, Wbf, N_ * K_ / 8);
    gemm_qkv<<<768, 512, 0, stream>>>(Abf, Wbf, b_qkv, mask, KQ, KKT, VT);
    kv_ksum_partial<<<dim3(64, 16), 256, 0, stream>>>(VT, KKT, KVP, KSP);
    reduce_kv<<<256, 256, 0, stream>>>(KVP, KSP, KV, KSUM);
    attn_out<<<dim3(64, 16), 256, 0, stream>>>(KQ, KV, KSUM, (float*)d_out);
}

// Round 4
// 168.089 us; speedup vs baseline: 7.3303x; 1.0028x over previous
//
#include <hip/hip_runtime.h>

typedef unsigned short u16;
typedef short bf16x8 __attribute__((ext_vector_type(8)));
typedef float f32x4 __attribute__((ext_vector_type(4)));
typedef u16 u16x8 __attribute__((ext_vector_type(8)));
typedef u16 u16x4 __attribute__((ext_vector_type(4)));

#define B_ 4
#define S_ 4096
#define E_ 1024
#define H_ 16
#define D_ 64
#define M_ 16384
#define N_ 3072
#define K_ 1024

__device__ __forceinline__ u16 f2b(float f) {
    unsigned x = __builtin_bit_cast(unsigned, f);
    return (u16)((x + 0x7fffu + ((x >> 16) & 1u)) >> 16);   // RNE
}
__device__ __forceinline__ float b2f(u16 u) {
    unsigned x = ((unsigned)u) << 16;
    return __builtin_bit_cast(float, x);
}
__device__ __forceinline__ float phi_f(float x) { return x > 0.f ? x + 1.f : __expf(x); }

__device__ __forceinline__ void gload16(const void* g, void* l) {
    __builtin_amdgcn_global_load_lds((const __attribute__((address_space(1))) void*)g,
                                     (__attribute__((address_space(3))) void*)l, 16, 0, 0);
}

#define MEMFENCE asm volatile("" ::: "memory")

// ---------------- kernel 1: fp32 -> bf16 convert ----------------
__global__ void cvt_bf16(const float* __restrict__ in, u16* __restrict__ out, int n8) {
    int stride = gridDim.x * blockDim.x;
    for (int i = blockIdx.x * blockDim.x + threadIdx.x; i < n8; i += stride) {
        const float4* p = (const float4*)(in + (size_t)i * 8);
        float4 a = p[0], b = p[1];
        u16x8 o;
        o[0] = f2b(a.x); o[1] = f2b(a.y); o[2] = f2b(a.z); o[3] = f2b(a.w);
        o[4] = f2b(b.x); o[5] = f2b(b.y); o[6] = f2b(b.z); o[7] = f2b(b.w);
        *(u16x8*)(out + (size_t)i * 8) = o;
    }
}

// ---------------- kernel 2: QKV GEMM, 256^2 tile, 8-phase pipeline ----------------
// T2 (XOR-swizzled LDS via pre-swizzled global src + swizzled ds_read addr),
// T3+T4 (8 snake-quadrant phases, 1 half-tile stage/phase, vmcnt(4) at P4/P8),
// T5 (setprio around each 16-MFMA cluster).
// Region schedule (per K-tile-pair, tiles t in buf0 / t+1 in buf1):
//   P1 rd: A-lo(t),B01(t)   st: B01(t+1)->buf1
//   P2 rd: B23(t)           st: B23(t+1)->buf1
//   P3 rd: A-hi(t)          st: A-lo(t+2)->buf0   [A-lo last read P1]
//   P4 rd: B01(t) again     st: A-hi(t+2)->buf0   [A-hi last read P3]; vmcnt(4)
//   P5 rd: A-lo(t+1),B01(t+1) st: B01(t+2)->buf0  [B01 last read P4]
//   P6 rd: B23(t+1)         st: B23(t+2)->buf0    [B23 last read P2]
//   P7 rd: A-hi(t+1)        st: A-lo(t+3)->buf1
//   P8 rd: B01(t+1) again   st: A-hi(t+3)->buf1; vmcnt(4)
// Every stage-issue is barrier-after the region's last ds_read -> race-free.
// vmcnt(4)@P4 completes tile t+1 (12 outstanding -> oldest 8 done);
// vmcnt(4)@P8 completes tile t+2. Prefetch tile index clamps at 15 (the
// clamped junk stages obey the same positional invariant -> clobber-safe).

__global__ __launch_bounds__(512, 2) void gemm_qkv(
    const u16* __restrict__ Abf, const u16* __restrict__ Wbf,
    const float* __restrict__ bias, const float* __restrict__ mask,
    u16* __restrict__ KQ, u16* __restrict__ KKT, u16* __restrict__ VT)
{
    __shared__ __align__(16) char lds[131072];   // buf0: A 32K | B 32K ; buf1 same

    int wg  = blockIdx.x;
    int xcd = wg & 7, ii = wg >> 3;        // 768 % 8 == 0 -> bijective
    int tm  = xcd * 8 + ii / 12;
    int tn  = ii % 12;
    int m0 = tm << 8, n0 = tn << 8;

    int t = threadIdx.x;
    int l = t & 63, wid = t >> 6;
    int wr = wid >> 2, wc = wid & 3;       // 2 x 4 waves, per-wave C = 128x64
    int lg = l >> 4, lr = l & 15;

    int srow  = t >> 3;                    // 0..63 (row within 64-row chunk)
    int scolE = ((t & 7) ^ (srow & 7)) << 3;   // pre-swizzled source granule
    int t16   = t * 16;

    const u16* gA = Abf + (size_t)(m0 + srow) * K_ + scolE;
    const u16* gB = Wbf + (size_t)(n0 + srow) * K_ + scolE;

    const char* aB = lds + (wr * 128 + lr) * 128;
    const char* bB = lds + 32768 + (wc * 64 + lr) * 128;
    int pc0 = (lg * 16) ^ ((lr & 7) << 4);
    int pc1 = pc0 ^ 64;

    f32x4 acc[8][4] = {};
    bf16x8 av[4][2], bv2[2][2];

#define RD_A(BO, MI0) { _Pragma("unroll") for (int m_ = 0; m_ < 4; ++m_) { \
    av[m_][0] = *(const bf16x8*)(aB + (BO) + (MI0 + m_) * 2048 + pc0); \
    av[m_][1] = *(const bf16x8*)(aB + (BO) + (MI0 + m_) * 2048 + pc1); } }

#define RD_B(BO, NI0) { _Pragma("unroll") for (int n_ = 0; n_ < 2; ++n_) { \
    bv2[n_][0] = *(const bf16x8*)(bB + (BO) + (NI0 + n_) * 2048 + pc0); \
    bv2[n_][1] = *(const bf16x8*)(bB + (BO) + (NI0 + n_) * 2048 + pc1); } }

    // A-lo = chunks {0,2} (rows 0-63,128-191), A-hi = {1,3}
#define ST_A(TT, HI, BO) { \
    gload16(gA + (size_t)((HI) * 64) * K_ + (TT) * 64, lds + (BO) + (HI) * 8192 + t16); \
    gload16(gA + (size_t)((HI) * 64 + 128) * K_ + (TT) * 64, lds + (BO) + 16384 + (HI) * 8192 + t16); }

    // B01 = chunks {0,1} (rows 0-127), B23 = {2,3}
#define ST_B(TT, PR, BO) { \
    gload16(gB + (size_t)((PR) * 128) * K_ + (TT) * 64, lds + (BO) + 32768 + (PR) * 16384 + t16); \
    gload16(gB + (size_t)((PR) * 128 + 64) * K_ + (TT) * 64, lds + (BO) + 32768 + (PR) * 16384 + 8192 + t16); }

#define BAR { MEMFENCE; __builtin_amdgcn_s_barrier(); MEMFENCE; }

#define MM(MI0, NI0) { __builtin_amdgcn_s_setprio(1); \
    _Pragma("unroll") for (int m_ = 0; m_ < 4; ++m_) \
    _Pragma("unroll") for (int n_ = 0; n_ < 2; ++n_) \
    _Pragma("unroll") for (int h_ = 0; h_ < 2; ++h_) \
        acc[(MI0) + m_][(NI0) + n_] = __builtin_amdgcn_mfma_f32_16x16x32_bf16( \
            av[m_][h_], bv2[n_][h_], acc[(MI0) + m_][(NI0) + n_], 0, 0, 0); \
    __builtin_amdgcn_s_setprio(0); }

    // prologue: tile0 complete -> buf0, tile1 A -> buf1; wait tile0
    ST_A(0, 0, 0); ST_A(0, 1, 0); ST_B(0, 0, 0); ST_B(0, 1, 0);
    ST_A(1, 0, 65536); ST_A(1, 1, 65536);
    asm volatile("s_waitcnt vmcnt(4)" ::: "memory");
    __builtin_amdgcn_s_barrier();
    MEMFENCE;

#pragma unroll 1
    for (int kt = 0; kt < 16; kt += 2) {
        int tp2 = kt + 2 < 16 ? kt + 2 : 15;
        int tp3 = kt + 3 < 16 ? kt + 3 : 15;
        // P1
        RD_A(0, 0); RD_B(0, 0); ST_B(kt + 1, 0, 65536); BAR; MM(0, 0); BAR;
        // P2
        RD_B(0, 2); ST_B(kt + 1, 1, 65536); BAR; MM(0, 2); BAR;
        // P3
        RD_A(0, 4); ST_A(tp2, 0, 0); BAR; MM(4, 2); BAR;
        // P4
        RD_B(0, 0); ST_A(tp2, 1, 0);
        asm volatile("s_waitcnt vmcnt(4)" ::: "memory");
        BAR; MM(4, 0); BAR;
        // P5
        RD_A(65536, 0); RD_B(65536, 0); ST_B(tp2, 0, 0); BAR; MM(0, 0); BAR;
        // P6
        RD_B(65536, 2); ST_B(tp2, 1, 0); BAR; MM(0, 2); BAR;
        // P7
        RD_A(65536, 4); ST_A(tp3, 0, 65536); BAR; MM(4, 2); BAR;
        // P8
        RD_B(65536, 0); ST_A(tp3, 1, 65536);
        asm volatile("s_waitcnt vmcnt(4)" ::: "memory");
        BAR; MM(4, 0); BAR;
    }

    // ---------------- epilogue: bias + phi/mask + store ----------------
    int part = n0 >> 10;   // 0=q 1=k 2=v

    float bv[4];
#pragma unroll
    for (int ni = 0; ni < 4; ++ni) bv[ni] = bias[n0 + wc * 64 + ni * 16 + lr];

    if (part == 0) {
#pragma unroll
        for (int mi = 0; mi < 8; ++mi)
#pragma unroll
            for (int j = 0; j < 4; ++j) {
                int row = m0 + wr * 128 + mi * 16 + lg * 4 + j;
#pragma unroll
                for (int ni = 0; ni < 4; ++ni) {
                    int col = n0 + wc * 64 + ni * 16 + lr;
                    KQ[(size_t)row * E_ + col] = f2b(phi_f(acc[mi][ni][j] + bv[ni]));
                }
            }
    } else {
        u16* dst0 = (part == 1) ? KKT : VT;
        int b  = m0 >> 12;
        int sl = m0 & (S_ - 1);
        int h  = ((tn & 3) << 2) | wc;
#pragma unroll
        for (int mi = 0; mi < 8; ++mi) {
            int sbase = sl + wr * 128 + mi * 16 + lg * 4;
            float mk[4];
#pragma unroll
            for (int j = 0; j < 4; ++j)
                mk[j] = (part == 1) ? mask[m0 + wr * 128 + mi * 16 + lg * 4 + j] : 1.f;
#pragma unroll
            for (int ni = 0; ni < 4; ++ni) {
                u16x4 o;
#pragma unroll
                for (int j = 0; j < 4; ++j) {
                    float v = acc[mi][ni][j] + bv[ni];
                    if (part == 1) v = phi_f(v * mk[j]);
                    o[j] = f2b(v);
                }
                int d = ni * 16 + lr;
                *(u16x4*)(dst0 + ((size_t)((b * H_ + h) * D_ + d)) * S_ + sbase) = o;
            }
        }
    }
}

// ---------------- kernel 3: kv + ksum partials over s-chunks ----------------
__global__ __launch_bounds__(256) void kv_ksum_partial(
    const u16* __restrict__ VT, const u16* __restrict__ KKT,
    float* __restrict__ KVP, float* __restrict__ KSP)
{
    __shared__ __align__(16) u16 smem[8192];   // As 4096 | Bs 4096
    u16* As = smem;
    u16* Bs = smem + 4096;
    int bh = blockIdx.x;
    int ch = blockIdx.y;
    int s0 = ch << 8;
    int t = threadIdx.x;
    int l = t & 63, w = t >> 6;
    int lg = l >> 4, lr = l & 15;
    const u16* Ag = VT + (size_t)bh * (D_ * S_);
    const u16* Bg = KKT + (size_t)bh * (D_ * S_);
    int srow = t >> 3, scol = (t & 7) << 3;

    f32x4 acc[4] = {};
    float ks = 0.f;
    int kd = t >> 2;
    int kq4 = (t & 3) << 4;

    for (int kt = 0; kt < 4; ++kt) {
        __syncthreads();
        int sb = s0 + kt * 64;
#pragma unroll
        for (int i = 0; i < 2; ++i) {
            gload16(Ag + (size_t)(srow + i * 32) * S_ + sb + scol, As + i * 2048 + t * 8);
            gload16(Bg + (size_t)(srow + i * 32) * S_ + sb + scol, Bs + i * 2048 + t * 8);
        }
        __syncthreads();
#pragma unroll
        for (int i = 0; i < 16; ++i) ks += b2f(Bs[kd * 64 + kq4 + i]);
#pragma unroll
        for (int kh = 0; kh < 2; ++kh) {
            int ko = kh * 32 + lg * 8;
            bf16x8 a = *(const bf16x8*)&As[(w * 16 + lr) * 64 + ko];
#pragma unroll
            for (int ni = 0; ni < 4; ++ni) {
                bf16x8 bb = *(const bf16x8*)&Bs[(ni * 16 + lr) * 64 + ko];
                acc[ni] = __builtin_amdgcn_mfma_f32_16x16x32_bf16(a, bb, acc[ni], 0, 0, 0);
            }
        }
    }
    float* kvp = KVP + (size_t)ch * (64 * 4096) + bh * 4096;
#pragma unroll
    for (int ni = 0; ni < 4; ++ni)
#pragma unroll
        for (int j = 0; j < 4; ++j)
            kvp[(w * 16 + lg * 4 + j) * 64 + ni * 16 + lr] = acc[ni][j];
    ks += __shfl_xor(ks, 1);
    ks += __shfl_xor(ks, 2);
    if ((t & 3) == 0) KSP[ch * 4096 + bh * 64 + kd] = ks;
}

// ---------------- kernel 4: deterministic partial reduce ----------------
__global__ void reduce_kv(const float* __restrict__ KVP, const float* __restrict__ KSP,
                          float* __restrict__ KV, float* __restrict__ KSUM)
{
    int g = blockIdx.x * 256 + threadIdx.x;   // 65536 threads
#pragma unroll 1
    for (int i = g * 4; i < g * 4 + 4; ++i) {
        float s = 0.f;
#pragma unroll
        for (int c = 0; c < 16; ++c) s += KVP[(size_t)c * (64 * 4096) + i];
        KV[i] = s;
    }
    if (g < 4096) {
        float s = 0.f;
#pragma unroll
        for (int c = 0; c < 16; ++c) s += KSP[c * 4096 + g];
        KSUM[g] = s;
    }
}

// ---------------- kernel 5: attn = kq·[kv;ksum] , divide by den ----------------
__global__ __launch_bounds__(256) void attn_out(
    const u16* __restrict__ KQ, const float* __restrict__ KV,
    const float* __restrict__ KSUM, float* __restrict__ Out)
{
    __shared__ __align__(16) u16 kqs[16384];   // 256 x 64 bf16 (32 KB)
    __shared__ __align__(16) u16 bsm[5120];    // 80 x 64 bf16
    __shared__ float den[256];
    int bh = blockIdx.x, ch = blockIdx.y;
    int b = bh >> 4, h = bh & 15;
    int t = threadIdx.x;
    int l = t & 63, w = t >> 6;
    int lg = l >> 4, lr = l & 15;
    size_t row0 = (size_t)b * S_ + ch * 256;
    int srow = t >> 3, scol = (t & 7) << 3;
#pragma unroll
    for (int i = 0; i < 8; ++i)
        gload16(KQ + (row0 + srow + i * 32) * E_ + h * 64 + scol, kqs + i * 2048 + t * 8);

    const float* kvg = KV + bh * 4096;
#pragma unroll
    for (int ii = 0; ii < 16; ii += 4) {
        float4 v = *(const float4*)(kvg + t * 16 + ii);
        u16x4 o; o[0] = f2b(v.x); o[1] = f2b(v.y); o[2] = f2b(v.z); o[3] = f2b(v.w);
        *(u16x4*)&bsm[t * 16 + ii] = o;
    }
    if (t < 64) bsm[4096 + t] = f2b(KSUM[bh * 64 + t]);
    for (int i = t; i < 960; i += 256) bsm[4160 + i] = 0;
    __syncthreads();

    f32x4 acc[4][5] = {};
#pragma unroll
    for (int kh = 0; kh < 2; ++kh) {
        int ko = kh * 32 + lg * 8;
        bf16x8 af[4];
#pragma unroll
        for (int mi = 0; mi < 4; ++mi)
            af[mi] = *(const bf16x8*)&kqs[(w * 64 + mi * 16 + lr) * 64 + ko];
#pragma unroll
        for (int ni = 0; ni < 5; ++ni) {
            bf16x8 bb = *(const bf16x8*)&bsm[(ni * 16 + lr) * 64 + ko];
#pragma unroll
            for (int mi = 0; mi < 4; ++mi)
                acc[mi][ni] = __builtin_amdgcn_mfma_f32_16x16x32_bf16(af[mi], bb, acc[mi][ni], 0, 0, 0);
        }
    }
    if (lr == 0) {
#pragma unroll
        for (int mi = 0; mi < 4; ++mi)
#pragma unroll
            for (int j = 0; j < 4; ++j)
                den[w * 64 + mi * 16 + lg * 4 + j] = acc[mi][4][j];
    }
    __syncthreads();
#pragma unroll
    for (int mi = 0; mi < 4; ++mi)
#pragma unroll
        for (int j = 0; j < 4; ++j) {
            int sl = w * 64 + mi * 16 + lg * 4 + j;
            float z = 1.f / (den[sl] + 1e-6f);
            float* op = Out + (row0 + sl) * E_ + h * 64;
#pragma unroll
            for (int ni = 0; ni < 4; ++ni)
                op[ni * 16 + lr] = acc[mi][ni][j] * z;
        }
}

extern "C" void kernel_launch(void* const* d_in, const int* in_sizes, int n_in,
                              void* d_out, int out_size, void* d_ws, size_t ws_size,
                              hipStream_t stream)
{
    const float* inputs = (const float*)d_in[0];
    const float* mask   = (const float*)d_in[1];
    const float* w_qkv  = (const float*)d_in[2];
    const float* b_qkv  = (const float*)d_in[3];

    u16* Abf = (u16*)d_ws;                      // 16777216 bf16
    u16* Wbf = Abf + (size_t)M_ * K_;           // 3145728 bf16
    u16* KQ  = Wbf + (size_t)N_ * K_;           // 16777216 bf16
    float* KVP  = (float*)(KQ + (size_t)M_ * E_);   // 16*262144 f32
    float* KSP  = KVP + 16 * 64 * 4096;             // 16*4096 f32
    float* KV   = KSP + 16 * 4096;                  // 262144 f32
    float* KSUM = KV + 64 * 4096;                   // 4096 f32

    u16* KKT = (u16*)d_out;
    u16* VT  = KKT + (size_t)M_ * E_;

    cvt_bf16<<<2048, 256, 0, stream>>>(inputs, Abf, M_ * K_ / 8);
    cvt_bf16<<<768, 256, 0, stream>>>(w_qkv, Wbf, N_ * K_ / 8);
    gemm_qkv<<<768, 512, 0, stream>>>(Abf, Wbf, b_qkv, mask, KQ, KKT, VT);
    kv_ksum_partial<<<dim3(64, 16), 256, 0, stream>>>(VT, KKT, KVP, KSP);
    reduce_kv<<<256, 256, 0, stream>>>(KVP, KSP, KV, KSUM);
    attn_out<<<dim3(64, 16), 256, 0, stream>>>(KQ, KV, KSUM, (float*)d_out);
}